// Round 17
// baseline (3568.789 us; speedup 1.0000x reference)
//
#include <hip/hip_runtime.h>

// Two-layer tanh RNN, H=32, B=64, T=16384. Latency-bound sequential scan.
//
// Round-33: batch-braid + sched_barrier(0) fence lattice.
// Model (validated R17..R32): step = ~2.3 cyc/instr issue + ~160 cyc chain
// stall. The stall only falls if PROGRAM ORDER interleaves independent
// work finely: compiler won't (R21), HW scheduler won't (R22). This round
// forces it: each wave carries TWO batch elements (b0=2*blk, b1=2*blk+1;
// 32 blocks), per-batch code bit-identical to green R31 (1836 us, absmax
// 3.906e-3), duplicated and interleaved in ~10 fence groups per step:
//   {seeds,pack0,pack1} F {trans0:8rl+8bperm} F {trans1} F {dot0 lo} F
//   {dot1 lo} F {dot0 hi,tree,publish0} F {dot1 hi,tree,publish1,exp0} F
//   {exp1, tail0} F {tail1}
// Every chain link has >=8-16 other-chain ops between producer and
// consumer. Weights are batch-independent (shared VGPRs). absmax must be
// EXACTLY 0.00390625 (same math per batch; batches independent).
// All R31 parts retained: TSC pre-folded weights/seeds, uval-in-seed,
// cvt_pkrtz pack, BCASTMIX transport, u-window ring, epilogues.

#define T_LEN 16384
#define B_SZ  64
#define NW    (T_LEN / 32)   // 512 windows
#define TSC   2.885390082f   // 2*log2(e)

#if __has_builtin(__builtin_amdgcn_exp2f)
#define EXP2(x) __builtin_amdgcn_exp2f(x)
#else
#define EXP2(x) exp2f(x)
#endif

#if __has_builtin(__builtin_amdgcn_sched_barrier)
#define SCHED_FENCE() __builtin_amdgcn_sched_barrier(0)
#else
#define SCHED_FENCE()
#endif

typedef _Float16 h2 __attribute__((ext_vector_type(2)));

__device__ __forceinline__ float rl(float v, int lane) {
  return __int_as_float(__builtin_amdgcn_readlane(__float_as_int(v), lane));
}

__device__ __forceinline__ h2 rl_h2(h2 v, int lane) {
  int o = __builtin_amdgcn_readlane(__builtin_bit_cast(int, v), lane);
  return __builtin_bit_cast(h2, o);
}

// Wave-uniform broadcast via the LDS crossbar (conflict-free mode).
__device__ __forceinline__ h2 bperm_h2(int byteaddr, h2 v) {
  int o = __builtin_amdgcn_ds_bpermute(byteaddr, __builtin_bit_cast(int, v));
  return __builtin_bit_cast(h2, o);
}

// quad_perm([1,0,3,2]): each lane sees its pair-neighbor's value.
__device__ __forceinline__ float pair_swap(float v) {
  int t = __builtin_amdgcn_update_dpp(0, __float_as_int(v), 0xB1, 0xF, 0xF, true);
  return __int_as_float(t);
}

#if __has_builtin(__builtin_amdgcn_fdot2)
#define FDOT2(a, b, c) __builtin_amdgcn_fdot2((a), (b), (c), false)
#else
#define FDOT2(a, b, c) \
  fmaf((float)(a).x, (float)(b).x, fmaf((float)(a).y, (float)(b).y, (c)))
#endif

// Pack this lane's state with its pair-neighbor: even lane 2j ends with
// (h[2j], h[2j+1]). DPP on f32 first, then ONE packed convert (RTZ).
__device__ __forceinline__ h2 pack_state(float hcur) {
  float hsw = pair_swap(hcur);
#if __has_builtin(__builtin_amdgcn_cvt_pkrtz)
  return __builtin_bit_cast(h2, __builtin_amdgcn_cvt_pkrtz(hcur, hsw));
#else
  h2 p; p.x = (_Float16)hcur; p.y = (_Float16)hsw; return p;
#endif
}

// Dual-pipe 16-pair transport (R31): pairs 0-7 via readlane, 8-15 via
// uniform bpermute, interleaved.
#define BCASTMIX(dst, src_pk)                                  \
  _Pragma("unroll")                                            \
  for (int j_ = 0; j_ < 8; ++j_) {                             \
    (dst)[j_]     = rl_h2((src_pk), 2 * j_);                   \
    (dst)[j_ + 8] = bperm_h2(64 + 8 * j_, (src_pk));           \
  }

// 8 dot2 (half of the 32-dot), accumulation order identical to R31's
// dot32h: B=0 covers w0..w7 (a0: w0,w4), B=2 covers w8..w15 (a0: w8,w12).
#define DOT8(A0, A1, A2, A3, W, HB, B)                         \
  A0 = FDOT2((W)[4*(B)+0], (HB)[4*(B)+0], A0);                 \
  A1 = FDOT2((W)[4*(B)+1], (HB)[4*(B)+1], A1);                 \
  A2 = FDOT2((W)[4*(B)+2], (HB)[4*(B)+2], A2);                 \
  A3 = FDOT2((W)[4*(B)+3], (HB)[4*(B)+3], A3);                 \
  A0 = FDOT2((W)[4*(B)+4], (HB)[4*(B)+4], A0);                 \
  A1 = FDOT2((W)[4*(B)+5], (HB)[4*(B)+5], A1);                 \
  A2 = FDOT2((W)[4*(B)+6], (HB)[4*(B)+6], A2);                 \
  A3 = FDOT2((W)[4*(B)+7], (HB)[4*(B)+7], A3);

// Full 32-dot for epilogues (bit-identical order).
__device__ __forceinline__ float dot32h(const h2* w, const h2* hb, float seed) {
  float a0 = seed, a1 = 0.f, a2 = 0.f, a3 = 0.f;
  DOT8(a0, a1, a2, a3, w, hb, 0);
  DOT8(a0, a1, a2, a3, w, hb, 2);
  return (a0 + a1) + (a2 + a3);
}

__global__ __launch_bounds__(128, 1) void rnn2_kernel(
    const float* __restrict__ x,    const float* __restrict__ hs,
    const float* __restrict__ Wih0, const float* __restrict__ Whh0,
    const float* __restrict__ bih0, const float* __restrict__ bhh0,
    const float* __restrict__ Wih1, const float* __restrict__ Whh1,
    const float* __restrict__ bih1, const float* __restrict__ bhh1,
    const float* __restrict__ Wout, const float* __restrict__ bout,
    float* __restrict__ out)
{
  __shared__ __align__(16) float uwin[2][2][1024]; // [batch][parity][slot]
  __shared__ __align__(16) float scratch[1024];    // sink (never read)

  const int  tid = (int)threadIdx.x;
  const int  wv  = tid >> 6;            // 0 = wave A (h0), 1 = wave B (h1)
  const int  m   = tid & 63;
  const int  r   = m & 31;              // row owned by this lane
  const bool hi  = (m >= 32);           // secondary-matrix half
  const int  b0  = (int)blockIdx.x * 2;
  const int  b1  = b0 + 1;

  // Per-lane weights (batch-independent, shared by both chains), TSC
  // pre-folded as in R31:
  //  A: lo = TSC*Whh0[r], hi = TSC*Wih1[r]; B: lo = TSC*Whh1[r], hi = Wout.
  const float* pw = (wv == 0) ? (hi ? (Wih1 + r * 32) : (Whh0 + r * 32))
                              : (hi ? Wout : (Whh1 + r * 32));
  const float wsc = (wv == 0) ? TSC : (hi ? 1.f : TSC);
  h2 w[16];
#pragma unroll
  for (int k = 0; k < 8; ++k) {
    float4 q = ((const float4*)pw)[k];
    w[2 * k].x     = (_Float16)(q.x * wsc);
    w[2 * k].y     = (_Float16)(q.y * wsc);
    w[2 * k + 1].x = (_Float16)(q.z * wsc);
    w[2 * k + 1].y = (_Float16)(q.w * wsc);
  }

  float xw = 0.f, binv = 0.f;
  if (wv == 0) {
    if (hi) binv = TSC * (bih1[r] + bhh1[r]);
    else  { binv = TSC * (bih0[r] + bhh0[r]); xw = TSC * Wih0[r]; }
  }
  const float bo = bout[0];

  // States: lane k<32 holds h[k] per batch.
  float hc0 = (wv == 0) ? hs[b0 * 32 + r] : hs[2048 + b0 * 32 + r];
  float hc1 = (wv == 0) ? hs[b1 * 32 + r] : hs[2048 + b1 * 32 + r];

  // Wave A publish pointers per batch & parity.
  float* upA[2][2];
  upA[0][0] = hi ? &uwin[0][0][r] : &scratch[r];
  upA[0][1] = hi ? &uwin[0][1][r] : &scratch[r];
  upA[1][0] = hi ? &uwin[1][0][r] : &scratch[r];
  upA[1][1] = hi ? &uwin[1][1][r] : &scratch[r];

  const float* xb0  = x + (size_t)b0 * T_LEN;
  const float* xb1  = x + (size_t)b1 * T_LEN;
  float*       op0  = out + (size_t)b0 * T_LEN;
  float*       op1  = out + (size_t)b1 * T_LEN;
  float*       hf   = out + (size_t)B_SZ * T_LEN;    // h_final [2,B,H]

  float ob0 = 0.f, ob1 = 0.f;
  float xc0 = 0.f, xc1 = 0.f;
  if (wv == 0) { xc0 = xb0[m]; xc1 = xb1[m]; }

  for (int wdx = 0; wdx <= NW; ++wdx) {
    if (wv == 0) {
      if (wdx < NW) {
        float xn0 = 0.f, xn1 = 0.f;
        if (wdx + 1 < NW) {
          int xi = 32 * (wdx + 1) + m; if (xi > T_LEN - 1) xi = T_LEN - 1;
          xn0 = xb0[xi]; xn1 = xb1[xi];
        }
        float* up0 = upA[0][wdx & 1];
        float* up1 = upA[1][wdx & 1];
#pragma unroll 4
        for (int t2 = 0; t2 < 32; ++t2) {
          float xv0 = rl(xc0, t2);
          float xv1 = rl(xc1, t2);
          float sd0 = fmaf(xv0, xw, binv);
          float sd1 = fmaf(xv1, xw, binv);
          h2 hp0 = pack_state(hc0);
          h2 hp1 = pack_state(hc1);
          SCHED_FENCE();
          h2 hb0[16]; BCASTMIX(hb0, hp0);
          SCHED_FENCE();
          h2 hb1[16]; BCASTMIX(hb1, hp1);
          SCHED_FENCE();
          float a00 = sd0, a01 = 0.f, a02 = 0.f, a03 = 0.f;
          DOT8(a00, a01, a02, a03, w, hb0, 0);
          SCHED_FENCE();
          float a10 = sd1, a11 = 0.f, a12 = 0.f, a13 = 0.f;
          DOT8(a10, a11, a12, a13, w, hb1, 0);
          SCHED_FENCE();
          DOT8(a00, a01, a02, a03, w, hb0, 2);
          float ac0 = (a00 + a01) + (a02 + a03);
          up0[t2 * 32] = ac0;                 // publish u0 (hi) / sink
          SCHED_FENCE();
          DOT8(a10, a11, a12, a13, w, hb1, 2);
          float ac1 = (a10 + a11) + (a12 + a13);
          up1[t2 * 32] = ac1;                 // publish u1 (hi) / sink
          float e0 = EXP2(ac0);
          SCHED_FENCE();
          float e1 = EXP2(ac1);
          hc0 = fmaf(-2.f, __builtin_amdgcn_rcpf(e0 + 1.f), 1.f);
          SCHED_FENCE();
          hc1 = fmaf(-2.f, __builtin_amdgcn_rcpf(e1 + 1.f), 1.f);
        }
        xc0 = xn0; xc1 = xn1;
      }
    } else {
      if (wdx >= 1) {
        const int wb = wdx - 1;               // steps t = 32*wb-1 ..
        const float* ub0 = &uwin[0][wb & 1][r];
        const float* ub1 = &uwin[1][wb & 1][r];
        float uv0 = ub0[0];
        float uv1 = ub1[0];
#pragma unroll 4
        for (int t2 = 0; t2 < 32; ++t2) {
          const int t = 32 * wb - 1 + t2;
          h2 hp0 = pack_state(hc0);
          h2 hp1 = pack_state(hc1);
          float un0 = ub0[((t2 + 1) & 31) * 32];   // pipelined u-reads
          float un1 = ub1[((t2 + 1) & 31) * 32];
          SCHED_FENCE();
          h2 hb0[16]; BCASTMIX(hb0, hp0);
          SCHED_FENCE();
          h2 hb1[16]; BCASTMIX(hb1, hp1);
          SCHED_FENCE();
          float a00 = hi ? 0.f : uv0, a01 = 0.f, a02 = 0.f, a03 = 0.f;
          DOT8(a00, a01, a02, a03, w, hb0, 0);
          SCHED_FENCE();
          float a10 = hi ? 0.f : uv1, a11 = 0.f, a12 = 0.f, a13 = 0.f;
          DOT8(a10, a11, a12, a13, w, hb1, 0);
          SCHED_FENCE();
          DOT8(a00, a01, a02, a03, w, hb0, 2);
          float ac0 = (a00 + a01) + (a02 + a03);
          ob0 = (m == 32 + t2) ? ac0 : ob0;
          SCHED_FENCE();
          DOT8(a10, a11, a12, a13, w, hb1, 2);
          float ac1 = (a10 + a11) + (a12 + a13);
          ob1 = (m == 32 + t2) ? ac1 : ob1;
          float e0 = EXP2(ac0);
          SCHED_FENCE();
          float e1 = EXP2(ac1);
          float h0n = fmaf(-2.f, __builtin_amdgcn_rcpf(e0 + 1.f), 1.f);
          if (t >= 0) hc0 = h0n;
          uv0 = un0;
          SCHED_FENCE();
          float h1n = fmaf(-2.f, __builtin_amdgcn_rcpf(e1 + 1.f), 1.f);
          if (t >= 0) hc1 = h1n;
          uv1 = un1;
        }
        const int idx = 32 * wb - 2 + r;      // hi lane 32+k holds out(idx)
        if (hi && idx >= 0) { op0[idx] = ob0 + bo; op1[idx] = ob1 + bo; }
      }
    }
    __syncthreads();   // window handoff (uwin parity swap)
  }

  // Epilogue 1 (wave A): publish TSC*u(T-1) per batch; h_final L0.
  if (wv == 0) {
    h2 hp0 = pack_state(hc0);
    h2 hb0[16]; BCASTMIX(hb0, hp0);
    float a0 = dot32h(w, hb0, binv);
    if (hi) uwin[0][0][r] = a0;
    else    hf[b0 * 32 + r] = hc0;
    h2 hp1 = pack_state(hc1);
    h2 hb1[16]; BCASTMIX(hb1, hp1);
    float a1 = dot32h(w, hb1, binv);
    if (hi) uwin[1][0][r] = a1;
    else    hf[b1 * 32 + r] = hc1;
  }
  __syncthreads();

  // Epilogue 2 (wave B): h1(T-1), out(T-2), out(T-1), h_final L1 per batch.
  if (wv == 1) {
    {
      float uT = uwin[0][0][r];
      h2 hp = pack_state(hc0);
      h2 hb[16]; BCASTMIX(hb, hp);
      float acc = dot32h(w, hb, hi ? 0.f : uT);
      if (m == 32) op0[T_LEN - 2] = acc + bo;
      float e = EXP2(acc);
      float h1T = fmaf(-2.f, __builtin_amdgcn_rcpf(e + 1.f), 1.f);
      h2 hp2 = pack_state(h1T);
      h2 hb2[16]; BCASTMIX(hb2, hp2);
      float acc2 = dot32h(w, hb2, 0.f);
      if (m == 32) op0[T_LEN - 1] = acc2 + bo;
      if (!hi) hf[2048 + b0 * 32 + r] = h1T;
    }
    {
      float uT = uwin[1][0][r];
      h2 hp = pack_state(hc1);
      h2 hb[16]; BCASTMIX(hb, hp);
      float acc = dot32h(w, hb, hi ? 0.f : uT);
      if (m == 32) op1[T_LEN - 2] = acc + bo;
      float e = EXP2(acc);
      float h1T = fmaf(-2.f, __builtin_amdgcn_rcpf(e + 1.f), 1.f);
      h2 hp2 = pack_state(h1T);
      h2 hb2[16]; BCASTMIX(hb2, hp2);
      float acc2 = dot32h(w, hb2, 0.f);
      if (m == 32) op1[T_LEN - 1] = acc2 + bo;
      if (!hi) hf[2048 + b1 * 32 + r] = h1T;
    }
  }
}

extern "C" void kernel_launch(void* const* d_in, const int* in_sizes, int n_in,
                              void* d_out, int out_size, void* d_ws, size_t ws_size,
                              hipStream_t stream) {
  rnn2_kernel<<<dim3(B_SZ / 2), dim3(128), 0, stream>>>(
      (const float*)d_in[0],  (const float*)d_in[1],  (const float*)d_in[2],
      (const float*)d_in[3],  (const float*)d_in[4],  (const float*)d_in[5],
      (const float*)d_in[6],  (const float*)d_in[7],  (const float*)d_in[8],
      (const float*)d_in[9],  (const float*)d_in[10], (const float*)d_in[11],
      (float*)d_out);
}

// Round 18
// 1833.314 us; speedup vs baseline: 1.9466x; 1.9466x over previous
//
#include <hip/hip_runtime.h>

// Two-layer tanh RNN, H=32, B=64, T=16384. Latency-bound sequential scan.
//
// Round-34: transport pipe-balance 6 readlane / 10 bpermute.
// Model v3 (fits all 17 prior configs): crosslane-VALU (readlane/DPP)
// ~8 cyc on VALU side; DS ops (bperm/ds_r/w) ~10 cyc on DS side; plain
// VALU/dot2 ~2; step ~ max(VALU side, DS side) + residual. Evidence:
// R18(16rl)=1952 = R26(16bperm)=1950; R31(8/8)=1836 (only split beats
// both); R29(DS-heavy)=1974; R33 braid=1.94x (no idle to hide).
// R31 sides: VALU ~130 vs DS ~90 -> VALU-bound. Balance at 6/10:
// VALU ~114, DS ~110. One-line transport change; bits, dot order, and
// everything else byte-identical to green R31 (1836 us) =>
// absmax must be EXACTLY 0.00390625.
// Retained: TSC pre-folded weights/seeds (4-dep tanh), uval folded into
// wave-B seed, cvt_pkrtz pack, unroll 8, u-window ring, epilogues.

#define T_LEN 16384
#define B_SZ  64
#define NW    (T_LEN / 32)   // 512 windows
#define TSC   2.885390082f   // 2*log2(e)

#if __has_builtin(__builtin_amdgcn_exp2f)
#define EXP2(x) __builtin_amdgcn_exp2f(x)
#else
#define EXP2(x) exp2f(x)
#endif

typedef _Float16 h2 __attribute__((ext_vector_type(2)));

__device__ __forceinline__ float rl(float v, int lane) {
  return __int_as_float(__builtin_amdgcn_readlane(__float_as_int(v), lane));
}

__device__ __forceinline__ h2 rl_h2(h2 v, int lane) {
  int o = __builtin_amdgcn_readlane(__builtin_bit_cast(int, v), lane);
  return __builtin_bit_cast(h2, o);
}

// Wave-uniform broadcast via the LDS crossbar (conflict-free mode): every
// lane pulls the pack register of lane (byteaddr>>2), byteaddr uniform.
__device__ __forceinline__ h2 bperm_h2(int byteaddr, h2 v) {
  int o = __builtin_amdgcn_ds_bpermute(byteaddr, __builtin_bit_cast(int, v));
  return __builtin_bit_cast(h2, o);
}

// quad_perm([1,0,3,2]): each lane sees its pair-neighbor's value.
__device__ __forceinline__ float pair_swap(float v) {
  int t = __builtin_amdgcn_update_dpp(0, __float_as_int(v), 0xB1, 0xF, 0xF, true);
  return __int_as_float(t);
}

// tanh with the 2*log2(e) scale PRE-FOLDED into the argument:
// tanh = 1 - 2/(2^v + 1), v = 2*log2(e)*x. 4-dep chain (mul removed).
__device__ __forceinline__ float tanh_pre(float v) {
  float e = EXP2(v);
  return fmaf(-2.f, __builtin_amdgcn_rcpf(e + 1.f), 1.f);
}

#if __has_builtin(__builtin_amdgcn_fdot2)
#define FDOT2(a, b, c) __builtin_amdgcn_fdot2((a), (b), (c), false)
#else
#define FDOT2(a, b, c) \
  fmaf((float)(a).x, (float)(b).x, fmaf((float)(a).y, (float)(b).y, (c)))
#endif

// Pack this lane's state with its pair-neighbor: even lane 2j ends with
// (h[2j], h[2j+1]). DPP on f32 first, then ONE packed convert (RTZ).
__device__ __forceinline__ h2 pack_state(float hcur) {
  float hsw = pair_swap(hcur);
#if __has_builtin(__builtin_amdgcn_cvt_pkrtz)
  return __builtin_bit_cast(h2, __builtin_amdgcn_cvt_pkrtz(hcur, hsw));
#else
  h2 p; p.x = (_Float16)hcur; p.y = (_Float16)hsw; return p;
#endif
}

// Pipe-balanced transport: pair j (source lane 2j, byte 8j). j=0..5 via
// readlane (VALU side), j=6..15 via uniform bpermute (DS side),
// interleaved so both pipes fill concurrently. 6/10 balances the sides
// (R31's 8/8 left VALU ~130 vs DS ~90).
#define BCASTMIX(dst, src_pk)                                  \
  do {                                                         \
    _Pragma("unroll")                                          \
    for (int j_ = 0; j_ < 6; ++j_) {                           \
      (dst)[j_]     = rl_h2((src_pk), 2 * j_);                 \
      (dst)[j_ + 6] = bperm_h2(48 + 8 * j_, (src_pk));         \
    }                                                          \
    _Pragma("unroll")                                          \
    for (int j_ = 12; j_ < 16; ++j_)                           \
      (dst)[j_] = bperm_h2(8 * j_, (src_pk));                  \
  } while (0)

// 32-term dot via 16 dot2, 4 accumulators (depth 4) + 2-level tree.
__device__ __forceinline__ float dot32h(const h2* w, const h2* hb, float seed) {
  float a0 = seed, a1 = 0.f, a2 = 0.f, a3 = 0.f;
#pragma unroll
  for (int j = 0; j < 4; ++j) {
    a0 = FDOT2(w[4 * j + 0], hb[4 * j + 0], a0);
    a1 = FDOT2(w[4 * j + 1], hb[4 * j + 1], a1);
    a2 = FDOT2(w[4 * j + 2], hb[4 * j + 2], a2);
    a3 = FDOT2(w[4 * j + 3], hb[4 * j + 3], a3);
  }
  return (a0 + a1) + (a2 + a3);
}

__global__ __launch_bounds__(128, 1) void rnn2_kernel(
    const float* __restrict__ x,    const float* __restrict__ hs,
    const float* __restrict__ Wih0, const float* __restrict__ Whh0,
    const float* __restrict__ bih0, const float* __restrict__ bhh0,
    const float* __restrict__ Wih1, const float* __restrict__ Whh1,
    const float* __restrict__ bih1, const float* __restrict__ bhh1,
    const float* __restrict__ Wout, const float* __restrict__ bout,
    float* __restrict__ out)
{
  __shared__ __align__(16) float uwin[2][1024];   // A->B; slot t2*32 + row
  __shared__ __align__(16) float scratch[1024];   // sink for lo-lane publishes

  const int  tid = (int)threadIdx.x;
  const int  wv  = tid >> 6;            // 0 = wave A (h0), 1 = wave B (h1)
  const int  m   = tid & 63;
  const int  r   = m & 31;              // row owned by this lane
  const bool hi  = (m >= 32);           // secondary-matrix half
  const int  b   = (int)blockIdx.x;

  // Per-lane full 32-float row, packed to 16 f16 pairs, with the tanh
  // input scale TSC pre-folded where the dot feeds tanh (or the published
  // u, which wave B consumes as a pre-scaled tanh seed):
  //  A: lo = TSC*Whh0[r], hi = TSC*Wih1[r]   (published u = TSC*u_raw)
  //  B: lo = TSC*Whh1[r], hi = Wout (raw; feeds out, not tanh)
  const float* pw = (wv == 0) ? (hi ? (Wih1 + r * 32) : (Whh0 + r * 32))
                              : (hi ? Wout : (Whh1 + r * 32));
  const float wsc = (wv == 0) ? TSC : (hi ? 1.f : TSC);
  h2 w[16];
#pragma unroll
  for (int k = 0; k < 8; ++k) {
    float4 q = ((const float4*)pw)[k];
    w[2 * k].x     = (_Float16)(q.x * wsc);
    w[2 * k].y     = (_Float16)(q.y * wsc);
    w[2 * k + 1].x = (_Float16)(q.z * wsc);
    w[2 * k + 1].y = (_Float16)(q.w * wsc);
  }

  float xw = 0.f, binv = 0.f;
  if (wv == 0) {
    if (hi) binv = TSC * (bih1[r] + bhh1[r]);    // u seed: TSC*b1
    else  { binv = TSC * (bih0[r] + bhh0[r]); xw = TSC * Wih0[r]; }
  }
  const float bo = bout[0];

  // State register: lane k (k<32) holds h[k] in f32 (raw, unscaled). Hi
  // lanes carry garbage copies; pack_state/BCASTMIX read even lanes 0..30.
  float hcur = (wv == 0) ? hs[b * 32 + r] : hs[2048 + b * 32 + r];

  // Wave A publish pointers: hi lanes -> uwin row r, lo lanes -> scratch.
  float* up0 = hi ? &uwin[0][r] : &scratch[r];
  float* up1 = hi ? &uwin[1][r] : &scratch[r];

  const float* xb   = x + (size_t)b * T_LEN;
  float*       outp = out + (size_t)b * T_LEN;       // outs[b*T + t]
  float*       hf   = out + (size_t)B_SZ * T_LEN;    // h_final [2,B,H]

  float obuf = 0.f;
  float xcur = 0.f;
  if (wv == 0) xcur = xb[m];            // window 0 chunk (lanes 0..31 used)

  for (int wdx = 0; wdx <= NW; ++wdx) {
    if (wv == 0) {
      if (wdx < NW) {
        // Prefetch next window's x chunk; consumed 32 steps from now.
        float xnext = 0.f;
        if (wdx + 1 < NW) {
          int xi = 32 * (wdx + 1) + m; if (xi > T_LEN - 1) xi = T_LEN - 1;
          xnext = xb[xi];
        }
        float* up = (wdx & 1) ? up1 : up0;
#pragma unroll 8
        for (int t2 = 0; t2 < 32; ++t2) {
          h2 hpk = pack_state(hcur);        // h0n(t-1) packed pairs
          h2 hb[16];
          BCASTMIX(hb, hpk);                // 6 readlane + 10 bperm
          float xv   = rl(xcur, t2);        // x(t)   (off-chain)
          float seed = fmaf(xv, xw, binv);  // lo: TSC*(x*W+b0); hi: TSC*b1
          float acc  = dot32h(w, hb, seed); // lo: tanh arg; hi: TSC*u(t-1)
          up[t2 * 32] = acc;                // hi publishes u; lo -> scratch
          hcur = tanh_pre(acc);             // lo lanes: h0n(t)
        }
        xcur = xnext;
      }
    } else {
      if (wdx >= 1) {
        const int wb = wdx - 1;             // steps t = 32*wb-1 .. 32*wb+30
        const float* ub = &uwin[wb & 1][r];
        float uval = ub[0];                 // TSC*u(32*wb-1)
#pragma unroll 8
        for (int t2 = 0; t2 < 32; ++t2) {
          const int t = 32 * wb - 1 + t2;
          h2 hpk = pack_state(hcur);        // h1n(t-1) packed pairs
          h2 hb[16];
          BCASTMIX(hb, hpk);                // 6 readlane + 10 bperm
          float sB  = hi ? 0.f : uval;      // uval folded into seed
          float acc = dot32h(w, hb, sB);    // lo: tanh arg; hi: out(t-1)-bo
          float unext = ub[((t2 + 1) & 31) * 32];  // pipelined u-read
          float h1n = tanh_pre(acc);
          obuf = (m == 32 + t2) ? acc : obuf;      // hi lane t2: out(t-1)-bo
          if (t >= 0) hcur = h1n;           // uniform guard (skips wb=0,t2=0)
          uval = unext;
        }
        const int idx = 32 * wb - 2 + r;    // hi lane 32+k holds out(32wb-2+k)
        if (hi && idx >= 0) outp[idx] = obuf + bo;   // coalesced store
      }
    }
    __syncthreads();   // window handoff (uwin parity swap)
  }

  // Epilogue 1 (wave A): publish TSC*u(T-1) from h0n(T-1); h_final L0.
  if (wv == 0) {
    h2 hpk = pack_state(hcur);              // h0n(T-1)
    h2 hb[16];
    BCASTMIX(hb, hpk);
    float acc = dot32h(w, hb, binv);        // hi: TSC*(b1 + Wih1.h0n(T-1))
    if (hi) uwin[0][r] = acc;
    else    hf[b * 32 + r] = hcur;          // h_final layer 0 (full f32)
  }
  __syncthreads();

  // Epilogue 2 (wave B): h1n(T-1), out(T-2), out(T-1), h_final L1.
  if (wv == 1) {
    float uT = uwin[0][r];                  // TSC*u(T-1)
    h2 hpk = pack_state(hcur);              // h1n(T-2)
    h2 hb[16];
    BCASTMIX(hb, hpk);
    float acc = dot32h(w, hb, hi ? 0.f : uT);
    if (m == 32) outp[T_LEN - 2] = acc + bo;      // Wout . h1n(T-2) (raw hi)
    float h1T = tanh_pre(acc);              // valid in lo lanes
    h2 hpk2 = pack_state(h1T);              // h1n(T-1)
    h2 hb2[16];
    BCASTMIX(hb2, hpk2);
    float acc2 = dot32h(w, hb2, 0.f);
    if (m == 32) outp[T_LEN - 1] = acc2 + bo;     // Wout . h1n(T-1)
    if (!hi) hf[2048 + b * 32 + r] = h1T;   // h_final layer 1 (full f32)
  }
}

extern "C" void kernel_launch(void* const* d_in, const int* in_sizes, int n_in,
                              void* d_out, int out_size, void* d_ws, size_t ws_size,
                              hipStream_t stream) {
  rnn2_kernel<<<dim3(B_SZ), dim3(128), 0, stream>>>(
      (const float*)d_in[0],  (const float*)d_in[1],  (const float*)d_in[2],
      (const float*)d_in[3],  (const float*)d_in[4],  (const float*)d_in[5],
      (const float*)d_in[6],  (const float*)d_in[7],  (const float*)d_in[8],
      (const float*)d_in[9],  (const float*)d_in[10], (const float*)d_in[11],
      (float*)d_out);
}